// Round 4
// baseline (50.748 us; speedup 1.0000x reference)
//
#include <hip/hip_runtime.h>
#include <hip/hip_bf16.h>
#include <math.h>

typedef __attribute__((ext_vector_type(8))) short short8;
typedef __attribute__((ext_vector_type(16))) float f32x16;

#define DHEAD 64
#define KVB 32
#define QB 32
#define SSEG 4   // KV segments (flash-decoding split)
#define NWF 4    // fallback waves/block

__device__ __forceinline__ unsigned pack2_bf16(float a, float b) {
  unsigned ua = __builtin_bit_cast(unsigned, a);
  unsigned ub = __builtin_bit_cast(unsigned, b);
  ua = (ua + 0x7fffu + ((ua >> 16) & 1u)) >> 16;
  ub = (ub + 0x7fffu + ((ub >> 16) & 1u)) >> 16;
  return (ua & 0xffffu) | (ub << 16);
}

union Frag { unsigned u[4]; short8 s; };

// ---------------- prep: K -> bf16 (same layout), V -> bf16 transposed ----------------
// 32-key tiles: (Lk/32, B) = 512 blocks of 256 threads.
__global__ __launch_bounds__(256)
void prep_kv(const float* __restrict__ K, const float* __restrict__ V,
             unsigned short* __restrict__ Kh, unsigned short* __restrict__ VT, int Lk) {
  __shared__ float Vs[32][65];
  const int b   = blockIdx.y;
  const int k0  = blockIdx.x * 32;
  const int tid = threadIdx.x;
  const size_t base = ((size_t)b * Lk + k0) * DHEAD;

  // K convert: 32 rows x 64 d = 2048 floats -> 256 short8 chunks (1/thread)
  {
    const float* src = K + base + (size_t)tid * 8;
    Frag fr;
    #pragma unroll
    for (int j = 0; j < 4; ++j) fr.u[j] = pack2_bf16(src[2 * j], src[2 * j + 1]);
    *(short8*)(Kh + base + (size_t)tid * 8) = fr.s;
  }
  // V tile -> LDS (coalesced)
  for (int e = tid; e < 32 * DHEAD; e += 256) Vs[e >> 6][e & 63] = V[base + e];
  __syncthreads();
  // VT[b][d][k] = V[b][k][d]; packed u32 pairs along k (coalesced per 16-thread group)
  unsigned* VT32 = (unsigned*)VT;
  for (int i = tid; i < 1024; i += 256) {
    const int d = i >> 4, jp = i & 15;
    VT32[(((size_t)b * DHEAD + d) * Lk + k0) / 2 + jp] =
        pack2_bf16(Vs[2 * jp][d], Vs[2 * jp + 1][d]);
  }
}

// ---------------- pass 1: one wave per (q-tile, batch, segment) ----------------
__global__ __launch_bounds__(64, 4)
void fa_seg(const float* __restrict__ Qg, const unsigned short* __restrict__ Khg,
            const unsigned short* __restrict__ VTg, const int* __restrict__ VL,
            float* __restrict__ OT, float* __restrict__ Mp, float* __restrict__ Lp,
            int Lq, int Lk, int nqt) {
  const int lane = threadIdx.x;
  const int l31  = lane & 31;
  const int hi   = lane >> 5;
  const int qt   = blockIdx.x;
  const int b    = blockIdx.y;
  const int sg   = blockIdx.z;
  const int vl   = VL[b];

  const int tilesPerSeg = (Lk / KVB) / SSEG;
  int nkb = (vl == 0) ? (Lk / KVB) : ((vl + KVB - 1) / KVB);
  if (nkb > Lk / KVB) nkb = Lk / KVB;
  const int tA = sg * tilesPerSeg;
  int tB = tA + tilesPerSeg; if (tB > nkb) tB = nkb;

  const size_t idx = ((size_t)(b * SSEG + sg) * nqt + qt);

  if (tA >= tB) {  // empty segment: publish (-inf, 0); combine skips O
    if (lane < 32) { Mp[idx * 32 + lane] = -INFINITY; Lp[idx * 32 + lane] = 0.f; }
    return;
  }

  const float* Qb = Qg + (size_t)b * Lq * DHEAD;
  const unsigned short* Kb  = Khg + (size_t)b * Lk * DHEAD;
  const unsigned short* VTb = VTg + (size_t)b * DHEAD * Lk;

  // Q fragments (B operand of S^T = K * Q^T). Fold scale (1/8) * log2(e).
  const float cQ = 0.125f * 1.4426950408889634f;
  short8 qf[4];
  {
    const float* qrow = Qb + (size_t)(qt * QB + l31) * DHEAD + hi * 8;
    #pragma unroll
    for (int kk = 0; kk < 4; ++kk) {
      Frag fr;
      #pragma unroll
      for (int j = 0; j < 4; ++j)
        fr.u[j] = pack2_bf16(qrow[kk * 16 + 2 * j] * cQ,
                             qrow[kk * 16 + 2 * j + 1] * cQ);
      qf[kk] = fr.s;
    }
  }

  f32x16 o0 = {};  // O^T rows d=0..31  (col = query = lane&31)
  f32x16 o1 = {};  // O^T rows d=32..63
  float m = -INFINITY;
  float l = 0.0f;
  const float MASKV = -1442695.04f;  // -1e6 * log2(e)

  for (int t = tA; t < tB; ++t) {
    const int key0 = t * KVB;

    short8 kf[4];
    #pragma unroll
    for (int kk = 0; kk < 4; ++kk)
      kf[kk] = *(const short8*)(Kb + (size_t)(key0 + l31) * DHEAD + kk * 16 + hi * 8);

    short8 vf0[2], vf1[2];
    #pragma unroll
    for (int kk = 0; kk < 2; ++kk) {
      const size_t ko = (size_t)key0 + kk * 16 + hi * 8;
      vf0[kk] = *(const short8*)(VTb + (size_t)l31 * Lk + ko);
      vf1[kk] = *(const short8*)(VTb + (size_t)(32 + l31) * Lk + ko);
    }

    f32x16 s = {};
    #pragma unroll
    for (int kk = 0; kk < 4; ++kk)
      s = __builtin_amdgcn_mfma_f32_32x32x16_bf16(kf[kk], qf[kk], s, 0, 0, 0);

    if (key0 + KVB > vl) {
      #pragma unroll
      for (int r = 0; r < 16; ++r) {
        const int key = key0 + (r & 3) + 8 * (r >> 2) + 4 * hi;
        if (key >= vl) s[r] = MASKV;
      }
    }

    // tile max (tree)
    float t0 = fmaxf(s[0], s[1]),  t1 = fmaxf(s[2], s[3]);
    float t2 = fmaxf(s[4], s[5]),  t3 = fmaxf(s[6], s[7]);
    float t4 = fmaxf(s[8], s[9]),  t5 = fmaxf(s[10], s[11]);
    float t6 = fmaxf(s[12], s[13]), t7 = fmaxf(s[14], s[15]);
    t0 = fmaxf(t0, t1); t2 = fmaxf(t2, t3); t4 = fmaxf(t4, t5); t6 = fmaxf(t6, t7);
    t0 = fmaxf(t0, t2); t4 = fmaxf(t4, t6);
    float tm = fmaxf(t0, t4);
    tm = fmaxf(tm, __shfl_xor(tm, 32));

    // exact defer-max: skip rescale when no lane's max grew (alpha would be 1)
    if (__any(tm > m)) {
      const float mnew  = fmaxf(m, tm);
      const float alpha = exp2f(m - mnew);  // first iter: exp2(-inf) = 0
      #pragma unroll
      for (int r = 0; r < 16; ++r) { o0[r] *= alpha; o1[r] *= alpha; }
      l *= alpha;
      m = mnew;
    }
    #pragma unroll
    for (int r = 0; r < 16; ++r) s[r] = exp2f(s[r] - m);
    float u0 = s[0] + s[1],  u1 = s[2] + s[3];
    float u2 = s[4] + s[5],  u3 = s[6] + s[7];
    float u4 = s[8] + s[9],  u5 = s[10] + s[11];
    float u6 = s[12] + s[13], u7 = s[14] + s[15];
    u0 += u1; u2 += u3; u4 += u5; u6 += u7; u0 += u2; u4 += u6;
    float sum = u0 + u4;
    sum += __shfl_xor(sum, 32);
    l += sum;

    // pack P into B-operand frags of O^T += V^T * P^T
    short8 pf[2];
    #pragma unroll
    for (int kk = 0; kk < 2; ++kk) {
      const unsigned A0 = pack2_bf16(s[8 * kk + 0], s[8 * kk + 1]);
      const unsigned B0 = pack2_bf16(s[8 * kk + 2], s[8 * kk + 3]);
      const unsigned C0 = pack2_bf16(s[8 * kk + 4], s[8 * kk + 5]);
      const unsigned D0 = pack2_bf16(s[8 * kk + 6], s[8 * kk + 7]);
      const unsigned sA = (unsigned)__shfl_xor((int)A0, 32);
      const unsigned sB = (unsigned)__shfl_xor((int)B0, 32);
      const unsigned sC = (unsigned)__shfl_xor((int)C0, 32);
      const unsigned sD = (unsigned)__shfl_xor((int)D0, 32);
      Frag fr;
      fr.u[0] = hi ? sC : A0;
      fr.u[1] = hi ? sD : B0;
      fr.u[2] = hi ? C0 : sA;
      fr.u[3] = hi ? D0 : sB;
      pf[kk] = fr.s;
    }

    #pragma unroll
    for (int kk = 0; kk < 2; ++kk) {
      o0 = __builtin_amdgcn_mfma_f32_32x32x16_bf16(vf0[kk], pf[kk], o0, 0, 0, 0);
      o1 = __builtin_amdgcn_mfma_f32_32x32x16_bf16(vf1[kk], pf[kk], o1, 0, 0, 0);
    }
  }

  // publish partial: m, l and O^T (d-major -> coalesced 128B stores)
  if (hi == 0) { Mp[idx * 32 + l31] = m; Lp[idx * 32 + l31] = l; }
  float* ot = OT + idx * (QB * DHEAD);
  #pragma unroll
  for (int r = 0; r < 16; ++r) {
    const int dr = (r & 3) + 8 * (r >> 2) + 4 * hi;
    ot[dr * 32 + l31]        = o0[r];
    ot[(dr + 32) * 32 + l31] = o1[r];
  }
}

// ---------------- pass 2: combine SSEG partials, transpose, store ----------------
__global__ __launch_bounds__(256)
void fa_combine(const float* __restrict__ OT, const float* __restrict__ Mp,
                const float* __restrict__ Lp, float* __restrict__ Og,
                int Lq, int nqt) {
  __shared__ float wq[SSEG][32];
  __shared__ float rL[32];
  __shared__ float T[64][33];
  const int qt  = blockIdx.x;
  const int b   = blockIdx.y;
  const int tid = threadIdx.x;

  if (tid < 32) {
    const int q = tid;
    float ms[SSEG], ls[SSEG];
    float M = -INFINITY;
    #pragma unroll
    for (int s = 0; s < SSEG; ++s) {
      const size_t idx = ((size_t)(b * SSEG + s) * nqt + qt);
      ms[s] = Mp[idx * 32 + q];
      ls[s] = Lp[idx * 32 + q];
      M = fmaxf(M, ms[s]);
    }
    float L = 0.f;
    #pragma unroll
    for (int s = 0; s < SSEG; ++s) {
      const float w = (ls[s] > 0.f) ? exp2f(ms[s] - M) : 0.f;
      wq[s][q] = w;
      L += ls[s] * w;
    }
    rL[q] = 1.f / L;
  }
  __syncthreads();

  for (int i = tid; i < QB * DHEAD; i += 256) {
    const int d = i >> 5, q = i & 31;
    float acc = 0.f;
    #pragma unroll
    for (int s = 0; s < SSEG; ++s) {
      const float w = wq[s][q];
      if (w != 0.f)  // guard: never read O of empty segments
        acc += OT[((size_t)(b * SSEG + s) * nqt + qt) * (QB * DHEAD) + i] * w;
    }
    T[d][q] = acc * rL[q];
  }
  __syncthreads();

  const size_t base = ((size_t)b * Lq + (size_t)qt * QB) * DHEAD;
  for (int j = tid; j < QB * DHEAD; j += 256)
    Og[base + j] = T[j & 63][j >> 6];
}

// ---------------- fallback (round-2 kernel, on-the-fly conversion) ----------------
__global__ __launch_bounds__(NWF * 64)
void fa_fwd(const float* __restrict__ Qg, const float* __restrict__ Kg,
            const float* __restrict__ Vg, const int* __restrict__ VL,
            float* __restrict__ Og, int Lq, int Lk) {
  __shared__ float OLs[NWF][QB][DHEAD + 1];
  __shared__ float mLs[NWF][QB];
  __shared__ float lLs[NWF][QB];

  const int tid  = threadIdx.x;
  const int w    = tid >> 6;
  const int lane = tid & 63;
  const int l31  = lane & 31;
  const int hi   = lane >> 5;
  const int q0   = blockIdx.x * QB;
  const int b    = blockIdx.y;
  const int vl   = VL[b];

  const float* Qb = Qg + (size_t)b * Lq * DHEAD;
  const float* Kb = Kg + (size_t)b * Lk * DHEAD;
  const float* Vb = Vg + (size_t)b * Lk * DHEAD;

  const float cQ = 0.125f * 1.4426950408889634f;
  short8 qf[4];
  {
    const float* qrow = Qb + (size_t)(q0 + l31) * DHEAD + hi * 8;
    #pragma unroll
    for (int kk = 0; kk < 4; ++kk) {
      Frag fr;
      #pragma unroll
      for (int j = 0; j < 4; ++j)
        fr.u[j] = pack2_bf16(qrow[kk * 16 + 2 * j] * cQ,
                             qrow[kk * 16 + 2 * j + 1] * cQ);
      qf[kk] = fr.s;
    }
  }

  f32x16 o0 = {};
  f32x16 o1 = {};
  float m = -INFINITY;
  float l = 0.0f;

  int nkb = (vl == 0) ? (Lk / KVB) : ((vl + KVB - 1) / KVB);
  if (nkb > Lk / KVB) nkb = Lk / KVB;
  const int nt = (nkb > w) ? ((nkb - w + NWF - 1) / NWF) : 0;

  const float MASKV = -1442695.04f;

  float kraw[32], vraw[32];

  if (nt > 0) {
    const float* krow = Kb + (size_t)(w * KVB + l31) * DHEAD + hi * 8;
    #pragma unroll
    for (int kk = 0; kk < 4; ++kk)
      #pragma unroll
      for (int j = 0; j < 8; ++j) kraw[kk * 8 + j] = krow[kk * 16 + j];
  }

  for (int t = 0; t < nt; ++t) {
    const int key0 = (w + t * NWF) * KVB;

    short8 kf[4];
    #pragma unroll
    for (int kk = 0; kk < 4; ++kk) {
      Frag fr;
      #pragma unroll
      for (int j = 0; j < 4; ++j)
        fr.u[j] = pack2_bf16(kraw[kk * 8 + 2 * j], kraw[kk * 8 + 2 * j + 1]);
      kf[kk] = fr.s;
    }

    #pragma unroll
    for (int kk = 0; kk < 2; ++kk) {
      const float* vrow = Vb + (size_t)(key0 + kk * 16 + hi * 8) * DHEAD + l31;
      #pragma unroll
      for (int j = 0; j < 8; ++j) {
        vraw[kk * 16 + j]     = vrow[j * DHEAD];
        vraw[kk * 16 + 8 + j] = vrow[j * DHEAD + 32];
      }
    }

    f32x16 s = {};
    #pragma unroll
    for (int kk = 0; kk < 4; ++kk)
      s = __builtin_amdgcn_mfma_f32_32x32x16_bf16(kf[kk], qf[kk], s, 0, 0, 0);

    if (t + 1 < nt) {
      const float* krow = Kb + (size_t)(key0 + NWF * KVB + l31) * DHEAD + hi * 8;
      #pragma unroll
      for (int kk = 0; kk < 4; ++kk)
        #pragma unroll
        for (int j = 0; j < 8; ++j) kraw[kk * 8 + j] = krow[kk * 16 + j];
    }

    if (key0 + KVB > vl) {
      #pragma unroll
      for (int r = 0; r < 16; ++r) {
        const int key = key0 + (r & 3) + 8 * (r >> 2) + 4 * hi;
        if (key >= vl) s[r] = MASKV;
      }
    }

    float t0 = fmaxf(s[0], s[1]),  t1 = fmaxf(s[2], s[3]);
    float t2 = fmaxf(s[4], s[5]),  t3 = fmaxf(s[6], s[7]);
    float t4 = fmaxf(s[8], s[9]),  t5 = fmaxf(s[10], s[11]);
    float t6 = fmaxf(s[12], s[13]), t7 = fmaxf(s[14], s[15]);
    t0 = fmaxf(t0, t1); t2 = fmaxf(t2, t3); t4 = fmaxf(t4, t5); t6 = fmaxf(t6, t7);
    t0 = fmaxf(t0, t2); t4 = fmaxf(t4, t6);
    float tm = fmaxf(t0, t4);
    tm = fmaxf(tm, __shfl_xor(tm, 32));
    const float mnew  = fmaxf(m, tm);
    const float alpha = exp2f(m - mnew);
    #pragma unroll
    for (int r = 0; r < 16; ++r) s[r] = exp2f(s[r] - mnew);
    float u0 = s[0] + s[1],  u1 = s[2] + s[3];
    float u2 = s[4] + s[5],  u3 = s[6] + s[7];
    float u4 = s[8] + s[9],  u5 = s[10] + s[11];
    float u6 = s[12] + s[13], u7 = s[14] + s[15];
    u0 += u1; u2 += u3; u4 += u5; u6 += u7; u0 += u2; u4 += u6;
    float sum = u0 + u4;
    sum += __shfl_xor(sum, 32);
    l = l * alpha + sum;
    m = mnew;
    #pragma unroll
    for (int r = 0; r < 16; ++r) { o0[r] *= alpha; o1[r] *= alpha; }

    short8 pf[2];
    #pragma unroll
    for (int kk = 0; kk < 2; ++kk) {
      const unsigned A0 = pack2_bf16(s[8 * kk + 0], s[8 * kk + 1]);
      const unsigned B0 = pack2_bf16(s[8 * kk + 2], s[8 * kk + 3]);
      const unsigned C0 = pack2_bf16(s[8 * kk + 4], s[8 * kk + 5]);
      const unsigned D0 = pack2_bf16(s[8 * kk + 6], s[8 * kk + 7]);
      const unsigned sA = (unsigned)__shfl_xor((int)A0, 32);
      const unsigned sB = (unsigned)__shfl_xor((int)B0, 32);
      const unsigned sC = (unsigned)__shfl_xor((int)C0, 32);
      const unsigned sD = (unsigned)__shfl_xor((int)D0, 32);
      Frag fr;
      fr.u[0] = hi ? sC : A0;
      fr.u[1] = hi ? sD : B0;
      fr.u[2] = hi ? C0 : sA;
      fr.u[3] = hi ? D0 : sB;
      pf[kk] = fr.s;
    }

    #pragma unroll
    for (int kk = 0; kk < 2; ++kk) {
      Frag f0, f1;
      #pragma unroll
      for (int j = 0; j < 4; ++j) {
        f0.u[j] = pack2_bf16(vraw[kk * 16 + 2 * j],     vraw[kk * 16 + 2 * j + 1]);
        f1.u[j] = pack2_bf16(vraw[kk * 16 + 8 + 2 * j], vraw[kk * 16 + 8 + 2 * j + 1]);
      }
      o0 = __builtin_amdgcn_mfma_f32_32x32x16_bf16(f0.s, pf[kk], o0, 0, 0, 0);
      o1 = __builtin_amdgcn_mfma_f32_32x32x16_bf16(f1.s, pf[kk], o1, 0, 0, 0);
    }
  }

  if (hi == 0) { mLs[w][l31] = m; lLs[w][l31] = l; }
  #pragma unroll
  for (int r = 0; r < 16; ++r) {
    const int dr = (r & 3) + 8 * (r >> 2) + 4 * hi;
    OLs[w][l31][dr]      = o0[r];
    OLs[w][l31][dr + 32] = o1[r];
  }
  __syncthreads();

  for (int e = tid; e < QB * DHEAD; e += NWF * 64) {
    const int q = e >> 6;
    const int d = e & 63;
    float M = mLs[0][q];
    #pragma unroll
    for (int ww = 1; ww < NWF; ++ww) M = fmaxf(M, mLs[ww][q]);
    float L = 0.f, acc = 0.f;
    #pragma unroll
    for (int ww = 0; ww < NWF; ++ww) {
      const float wgt = exp2f(mLs[ww][q] - M);
      L   += lLs[ww][q] * wgt;
      acc += OLs[ww][q][d] * wgt;
    }
    Og[((size_t)b * Lq + q0 + q) * DHEAD + d] = acc / L;
  }
}

extern "C" void kernel_launch(void* const* d_in, const int* in_sizes, int n_in,
                              void* d_out, int out_size, void* d_ws, size_t ws_size,
                              hipStream_t stream) {
  const float* Q  = (const float*)d_in[0];
  const float* K  = (const float*)d_in[1];
  const float* V  = (const float*)d_in[2];
  const int*   VL = (const int*)d_in[3];
  float* O = (float*)d_out;

  const int B  = in_sizes[3];                  // 8
  const int Lq = in_sizes[0] / (B * DHEAD);    // 2048
  const int Lk = in_sizes[1] / (B * DHEAD);    // 2048
  const int nqt = Lq / QB;                     // 64

  const size_t elems    = (size_t)B * Lk * DHEAD;                 // per tensor
  const size_t khBytes  = elems * 2;
  const size_t vtBytes  = elems * 2;
  const size_t nPart    = (size_t)B * SSEG * nqt;
  const size_t otBytes  = nPart * QB * DHEAD * sizeof(float);
  const size_t mlBytes  = nPart * QB * sizeof(float) * 2;
  const size_t need     = khBytes + vtBytes + otBytes + mlBytes;

  if (ws_size >= need) {
    unsigned short* Kh = (unsigned short*)d_ws;
    unsigned short* VT = Kh + elems;
    float* OT = (float*)((char*)d_ws + khBytes + vtBytes);
    float* Mp = OT + nPart * QB * DHEAD;
    float* Lp = Mp + nPart * QB;

    dim3 pgrid(Lk / 32, B);
    prep_kv<<<pgrid, 256, 0, stream>>>(K, V, Kh, VT, Lk);
    dim3 g1(nqt, B, SSEG);
    fa_seg<<<g1, 64, 0, stream>>>(Q, Kh, VT, VL, OT, Mp, Lp, Lq, Lk, nqt);
    dim3 g2(nqt, B);
    fa_combine<<<g2, 256, 0, stream>>>(OT, Mp, Lp, O, Lq, nqt);
  } else {
    dim3 grid(Lq / QB, B);
    fa_fwd<<<grid, NWF * 64, 0, stream>>>(Q, K, V, VL, O, Lq, Lk);
  }
}

// Round 5
// 49.382 us; speedup vs baseline: 1.0277x; 1.0277x over previous
//
#include <hip/hip_runtime.h>
#include <hip/hip_bf16.h>
#include <math.h>

typedef __attribute__((ext_vector_type(8))) short short8;
typedef __attribute__((ext_vector_type(16))) float f32x16;

#define DHEAD 64
#define KVB 32
#define QB 32
#define SSEG 4   // KV segments (flash-decoding split)
#define NW 4     // waves per block in fa_seg
#define NWF 4    // fallback waves/block

__device__ __forceinline__ unsigned pack2_bf16(float a, float b) {
  unsigned ua = __builtin_bit_cast(unsigned, a);
  unsigned ub = __builtin_bit_cast(unsigned, b);
  ua = (ua + 0x7fffu + ((ua >> 16) & 1u)) >> 16;
  ub = (ub + 0x7fffu + ((ub >> 16) & 1u)) >> 16;
  return (ua & 0xffffu) | (ub << 16);
}

union Frag { unsigned u[4]; short8 s; };

// ---- prep: Q -> bf16 (scale folded), K -> bf16, V -> bf16 transposed ----
// 32-row tiles: grid (max(Lk,Lq)/32, B), 256 threads.
__global__ __launch_bounds__(256)
void prep_qkv(const float* __restrict__ Q, const float* __restrict__ K,
              const float* __restrict__ V, unsigned short* __restrict__ Qh,
              unsigned short* __restrict__ Kh, unsigned short* __restrict__ VT,
              int Lq, int Lk) {
  __shared__ float Vs[32][65];
  const int b   = blockIdx.y;
  const int k0  = blockIdx.x * 32;
  const int tid = threadIdx.x;
  const float cQ = 0.125f * 1.4426950408889634f;  // (1/sqrt(64)) * log2(e)

  if (k0 < Lq) {  // Q convert (scale folded): 32 rows x 64 d -> 256 short8
    const size_t qbase = ((size_t)b * Lq + k0) * DHEAD;
    const float* src = Q + qbase + (size_t)tid * 8;
    Frag fr;
    #pragma unroll
    for (int j = 0; j < 4; ++j)
      fr.u[j] = pack2_bf16(src[2 * j] * cQ, src[2 * j + 1] * cQ);
    *(short8*)(Qh + qbase + (size_t)tid * 8) = fr.s;
  }

  if (k0 < Lk) {
    const size_t base = ((size_t)b * Lk + k0) * DHEAD;
    {  // K convert
      const float* src = K + base + (size_t)tid * 8;
      Frag fr;
      #pragma unroll
      for (int j = 0; j < 4; ++j) fr.u[j] = pack2_bf16(src[2 * j], src[2 * j + 1]);
      *(short8*)(Kh + base + (size_t)tid * 8) = fr.s;
    }
    // V tile -> LDS (coalesced)
    for (int e = tid; e < 32 * DHEAD; e += 256) Vs[e >> 6][e & 63] = V[base + e];
    __syncthreads();
    // VT[b][d][k] = V[b][k][d]; packed u32 pairs along k
    unsigned* VT32 = (unsigned*)VT;
    for (int i = tid; i < 1024; i += 256) {
      const int d = i >> 4, jp = i & 15;
      VT32[(((size_t)b * DHEAD + d) * Lk + k0) / 2 + jp] =
          pack2_bf16(Vs[2 * jp][d], Vs[2 * jp + 1][d]);
    }
  }
}

// ---- pass 1: block = (q-tile, batch, segment); NW waves split the segment ----
__global__ __launch_bounds__(NW * 64, 4)
void fa_seg(const unsigned short* __restrict__ Qhg, const unsigned short* __restrict__ Khg,
            const unsigned short* __restrict__ VTg, const int* __restrict__ VL,
            float* __restrict__ OT, float* __restrict__ Mp, float* __restrict__ Lp,
            int Lq, int Lk, int nqt) {
  __shared__ float OLs[NW][QB][DHEAD + 1];
  __shared__ float mLs[NW][QB];
  __shared__ float lLs[NW][QB];
  __shared__ float wq[NW][QB];

  const int tid  = threadIdx.x;
  const int w    = tid >> 6;
  const int lane = tid & 63;
  const int l31  = lane & 31;
  const int hi   = lane >> 5;
  const int qt   = blockIdx.x;
  const int b    = blockIdx.y;
  const int sg   = blockIdx.z;
  const int vl   = VL[b];

  const int tilesPerSeg = (Lk / KVB) / SSEG;
  int nkb = (vl == 0) ? (Lk / KVB) : ((vl + KVB - 1) / KVB);
  if (nkb > Lk / KVB) nkb = Lk / KVB;
  const int tA = sg * tilesPerSeg;
  int tB = tA + tilesPerSeg; if (tB > nkb) tB = nkb;

  const size_t idx = ((size_t)(b * SSEG + sg) * nqt + qt);

  if (tA >= tB) {  // empty segment: publish (-inf, 0); combine skips O
    if (tid < 32) { Mp[idx * 32 + tid] = -INFINITY; Lp[idx * 32 + tid] = 0.f; }
    return;
  }

  const unsigned short* Qb  = Qhg + (size_t)b * Lq * DHEAD;
  const unsigned short* Kb  = Khg + (size_t)b * Lk * DHEAD;
  const unsigned short* VTb = VTg + (size_t)b * DHEAD * Lk;

  // Q fragments: direct bf16 loads (scale pre-folded)
  short8 qf[4];
  #pragma unroll
  for (int kk = 0; kk < 4; ++kk)
    qf[kk] = *(const short8*)(Qb + (size_t)(qt * QB + l31) * DHEAD + kk * 16 + hi * 8);

  f32x16 o0 = {};  // O^T rows d=0..31  (col = query = lane&31)
  f32x16 o1 = {};  // O^T rows d=32..63
  float m = -INFINITY;
  float l = 0.0f;
  const float MASKV = -1442695.04f;  // -1e6 * log2(e)

  for (int t = tA + w; t < tB; t += NW) {
    const int key0 = t * KVB;

    short8 kf[4];
    #pragma unroll
    for (int kk = 0; kk < 4; ++kk)
      kf[kk] = *(const short8*)(Kb + (size_t)(key0 + l31) * DHEAD + kk * 16 + hi * 8);

    short8 vf0[2], vf1[2];
    #pragma unroll
    for (int kk = 0; kk < 2; ++kk) {
      const size_t ko = (size_t)key0 + kk * 16 + hi * 8;
      vf0[kk] = *(const short8*)(VTb + (size_t)l31 * Lk + ko);
      vf1[kk] = *(const short8*)(VTb + (size_t)(32 + l31) * Lk + ko);
    }

    f32x16 s = {};
    #pragma unroll
    for (int kk = 0; kk < 4; ++kk)
      s = __builtin_amdgcn_mfma_f32_32x32x16_bf16(kf[kk], qf[kk], s, 0, 0, 0);

    if (key0 + KVB > vl) {
      #pragma unroll
      for (int r = 0; r < 16; ++r) {
        const int key = key0 + (r & 3) + 8 * (r >> 2) + 4 * hi;
        if (key >= vl) s[r] = MASKV;
      }
    }

    // tile max (tree)
    float t0 = fmaxf(s[0], s[1]),  t1 = fmaxf(s[2], s[3]);
    float t2 = fmaxf(s[4], s[5]),  t3 = fmaxf(s[6], s[7]);
    float t4 = fmaxf(s[8], s[9]),  t5 = fmaxf(s[10], s[11]);
    float t6 = fmaxf(s[12], s[13]), t7 = fmaxf(s[14], s[15]);
    t0 = fmaxf(t0, t1); t2 = fmaxf(t2, t3); t4 = fmaxf(t4, t5); t6 = fmaxf(t6, t7);
    t0 = fmaxf(t0, t2); t4 = fmaxf(t4, t6);
    float tm = fmaxf(t0, t4);
    tm = fmaxf(tm, __shfl_xor(tm, 32));

    // exact defer-max: skip rescale when no lane's max grew (alpha would be 1)
    if (__any(tm > m)) {
      const float mnew  = fmaxf(m, tm);
      const float alpha = exp2f(m - mnew);  // first iter: exp2(-inf) = 0
      #pragma unroll
      for (int r = 0; r < 16; ++r) { o0[r] *= alpha; o1[r] *= alpha; }
      l *= alpha;
      m = mnew;
    }
    #pragma unroll
    for (int r = 0; r < 16; ++r) s[r] = exp2f(s[r] - m);
    float u0 = s[0] + s[1],  u1 = s[2] + s[3];
    float u2 = s[4] + s[5],  u3 = s[6] + s[7];
    float u4 = s[8] + s[9],  u5 = s[10] + s[11];
    float u6 = s[12] + s[13], u7 = s[14] + s[15];
    u0 += u1; u2 += u3; u4 += u5; u6 += u7; u0 += u2; u4 += u6;
    float sum = u0 + u4;
    sum += __shfl_xor(sum, 32);
    l += sum;

    // pack P into B-operand frags of O^T += V^T * P^T
    short8 pf[2];
    #pragma unroll
    for (int kk = 0; kk < 2; ++kk) {
      const unsigned A0 = pack2_bf16(s[8 * kk + 0], s[8 * kk + 1]);
      const unsigned B0 = pack2_bf16(s[8 * kk + 2], s[8 * kk + 3]);
      const unsigned C0 = pack2_bf16(s[8 * kk + 4], s[8 * kk + 5]);
      const unsigned D0 = pack2_bf16(s[8 * kk + 6], s[8 * kk + 7]);
      const unsigned sA = (unsigned)__shfl_xor((int)A0, 32);
      const unsigned sB = (unsigned)__shfl_xor((int)B0, 32);
      const unsigned sC = (unsigned)__shfl_xor((int)C0, 32);
      const unsigned sD = (unsigned)__shfl_xor((int)D0, 32);
      Frag fr;
      fr.u[0] = hi ? sC : A0;
      fr.u[1] = hi ? sD : B0;
      fr.u[2] = hi ? C0 : sA;
      fr.u[3] = hi ? D0 : sB;
      pf[kk] = fr.s;
    }

    #pragma unroll
    for (int kk = 0; kk < 2; ++kk) {
      o0 = __builtin_amdgcn_mfma_f32_32x32x16_bf16(vf0[kk], pf[kk], o0, 0, 0, 0);
      o1 = __builtin_amdgcn_mfma_f32_32x32x16_bf16(vf1[kk], pf[kk], o1, 0, 0, 0);
    }
  }

  // intra-block merge of NW wave-partials via LDS
  if (hi == 0) { mLs[w][l31] = m; lLs[w][l31] = l; }
  #pragma unroll
  for (int r = 0; r < 16; ++r) {
    const int dr = (r & 3) + 8 * (r >> 2) + 4 * hi;
    OLs[w][l31][dr]      = o0[r];
    OLs[w][l31][dr + 32] = o1[r];
  }
  __syncthreads();

  if (tid < 32) {
    const int q = tid;
    float M = mLs[0][q];
    #pragma unroll
    for (int ww = 1; ww < NW; ++ww) M = fmaxf(M, mLs[ww][q]);
    float L = 0.f;
    #pragma unroll
    for (int ww = 0; ww < NW; ++ww) {
      const float g = exp2f(mLs[ww][q] - M);  // empty wave: exp2(-inf)=0
      wq[ww][q] = g;
      L += lLs[ww][q] * g;
    }
    Mp[idx * 32 + q] = M;
    Lp[idx * 32 + q] = L;
  }
  __syncthreads();

  float* ot = OT + idx * (QB * DHEAD);
  for (int e = tid; e < QB * DHEAD; e += NW * 64) {
    const int q = e & 31, d = e >> 5;
    float acc = 0.f;
    #pragma unroll
    for (int ww = 0; ww < NW; ++ww) acc += OLs[ww][q][d] * wq[ww][q];
    ot[e] = acc;  // d-major: e = d*32+q (matches combine), coalesced
  }
}

// ---- pass 2: combine SSEG partials, transpose, store ----
__global__ __launch_bounds__(256)
void fa_combine(const float* __restrict__ OT, const float* __restrict__ Mp,
                const float* __restrict__ Lp, float* __restrict__ Og,
                int Lq, int nqt) {
  __shared__ float wq[SSEG][32];
  __shared__ float rL[32];
  __shared__ float T[64][33];
  const int qt  = blockIdx.x;
  const int b   = blockIdx.y;
  const int tid = threadIdx.x;

  if (tid < 32) {
    const int q = tid;
    float ms[SSEG], ls[SSEG];
    float M = -INFINITY;
    #pragma unroll
    for (int s = 0; s < SSEG; ++s) {
      const size_t idx = ((size_t)(b * SSEG + s) * nqt + qt);
      ms[s] = Mp[idx * 32 + q];
      ls[s] = Lp[idx * 32 + q];
      M = fmaxf(M, ms[s]);
    }
    float L = 0.f;
    #pragma unroll
    for (int s = 0; s < SSEG; ++s) {
      const float w = (ls[s] > 0.f) ? exp2f(ms[s] - M) : 0.f;
      wq[s][q] = w;
      L += ls[s] * w;
    }
    rL[q] = 1.f / L;
  }
  __syncthreads();

  for (int i = tid; i < QB * DHEAD; i += 256) {
    const int d = i >> 5, q = i & 31;
    float acc = 0.f;
    #pragma unroll
    for (int s = 0; s < SSEG; ++s) {
      const float w = wq[s][q];
      if (w != 0.f)  // never read O of empty segments
        acc += OT[((size_t)(b * SSEG + s) * nqt + qt) * (QB * DHEAD) + i] * w;
    }
    T[d][q] = acc * rL[q];
  }
  __syncthreads();

  const size_t base = ((size_t)b * Lq + (size_t)qt * QB) * DHEAD;
  for (int j = tid; j < QB * DHEAD; j += 256)
    Og[base + j] = T[j & 63][j >> 6];
}

// ---- fallback (round-2 kernel, on-the-fly conversion) ----
__global__ __launch_bounds__(NWF * 64)
void fa_fwd(const float* __restrict__ Qg, const float* __restrict__ Kg,
            const float* __restrict__ Vg, const int* __restrict__ VL,
            float* __restrict__ Og, int Lq, int Lk) {
  __shared__ float OLs[NWF][QB][DHEAD + 1];
  __shared__ float mLs[NWF][QB];
  __shared__ float lLs[NWF][QB];

  const int tid  = threadIdx.x;
  const int w    = tid >> 6;
  const int lane = tid & 63;
  const int l31  = lane & 31;
  const int hi   = lane >> 5;
  const int q0   = blockIdx.x * QB;
  const int b    = blockIdx.y;
  const int vl   = VL[b];

  const float* Qb = Qg + (size_t)b * Lq * DHEAD;
  const float* Kb = Kg + (size_t)b * Lk * DHEAD;
  const float* Vb = Vg + (size_t)b * Lk * DHEAD;

  const float cQ = 0.125f * 1.4426950408889634f;
  short8 qf[4];
  {
    const float* qrow = Qb + (size_t)(q0 + l31) * DHEAD + hi * 8;
    #pragma unroll
    for (int kk = 0; kk < 4; ++kk) {
      Frag fr;
      #pragma unroll
      for (int j = 0; j < 4; ++j)
        fr.u[j] = pack2_bf16(qrow[kk * 16 + 2 * j] * cQ,
                             qrow[kk * 16 + 2 * j + 1] * cQ);
      qf[kk] = fr.s;
    }
  }

  f32x16 o0 = {};
  f32x16 o1 = {};
  float m = -INFINITY;
  float l = 0.0f;

  int nkb = (vl == 0) ? (Lk / KVB) : ((vl + KVB - 1) / KVB);
  if (nkb > Lk / KVB) nkb = Lk / KVB;
  const int nt = (nkb > w) ? ((nkb - w + NWF - 1) / NWF) : 0;

  const float MASKV = -1442695.04f;

  float kraw[32], vraw[32];

  if (nt > 0) {
    const float* krow = Kb + (size_t)(w * KVB + l31) * DHEAD + hi * 8;
    #pragma unroll
    for (int kk = 0; kk < 4; ++kk)
      #pragma unroll
      for (int j = 0; j < 8; ++j) kraw[kk * 8 + j] = krow[kk * 16 + j];
  }

  for (int t = 0; t < nt; ++t) {
    const int key0 = (w + t * NWF) * KVB;

    short8 kf[4];
    #pragma unroll
    for (int kk = 0; kk < 4; ++kk) {
      Frag fr;
      #pragma unroll
      for (int j = 0; j < 4; ++j)
        fr.u[j] = pack2_bf16(kraw[kk * 8 + 2 * j], kraw[kk * 8 + 2 * j + 1]);
      kf[kk] = fr.s;
    }

    #pragma unroll
    for (int kk = 0; kk < 2; ++kk) {
      const float* vrow = Vb + (size_t)(key0 + kk * 16 + hi * 8) * DHEAD + l31;
      #pragma unroll
      for (int j = 0; j < 8; ++j) {
        vraw[kk * 16 + j]     = vrow[j * DHEAD];
        vraw[kk * 16 + 8 + j] = vrow[j * DHEAD + 32];
      }
    }

    f32x16 s = {};
    #pragma unroll
    for (int kk = 0; kk < 4; ++kk)
      s = __builtin_amdgcn_mfma_f32_32x32x16_bf16(kf[kk], qf[kk], s, 0, 0, 0);

    if (t + 1 < nt) {
      const float* krow = Kb + (size_t)(key0 + NWF * KVB + l31) * DHEAD + hi * 8;
      #pragma unroll
      for (int kk = 0; kk < 4; ++kk)
        #pragma unroll
        for (int j = 0; j < 8; ++j) kraw[kk * 8 + j] = krow[kk * 16 + j];
    }

    if (key0 + KVB > vl) {
      #pragma unroll
      for (int r = 0; r < 16; ++r) {
        const int key = key0 + (r & 3) + 8 * (r >> 2) + 4 * hi;
        if (key >= vl) s[r] = MASKV;
      }
    }

    float t0 = fmaxf(s[0], s[1]),  t1 = fmaxf(s[2], s[3]);
    float t2 = fmaxf(s[4], s[5]),  t3 = fmaxf(s[6], s[7]);
    float t4 = fmaxf(s[8], s[9]),  t5 = fmaxf(s[10], s[11]);
    float t6 = fmaxf(s[12], s[13]), t7 = fmaxf(s[14], s[15]);
    t0 = fmaxf(t0, t1); t2 = fmaxf(t2, t3); t4 = fmaxf(t4, t5); t6 = fmaxf(t6, t7);
    t0 = fmaxf(t0, t2); t4 = fmaxf(t4, t6);
    float tm = fmaxf(t0, t4);
    tm = fmaxf(tm, __shfl_xor(tm, 32));
    const float mnew  = fmaxf(m, tm);
    const float alpha = exp2f(m - mnew);
    #pragma unroll
    for (int r = 0; r < 16; ++r) s[r] = exp2f(s[r] - mnew);
    float u0 = s[0] + s[1],  u1 = s[2] + s[3];
    float u2 = s[4] + s[5],  u3 = s[6] + s[7];
    float u4 = s[8] + s[9],  u5 = s[10] + s[11];
    float u6 = s[12] + s[13], u7 = s[14] + s[15];
    u0 += u1; u2 += u3; u4 += u5; u6 += u7; u0 += u2; u4 += u6;
    float sum = u0 + u4;
    sum += __shfl_xor(sum, 32);
    l = l * alpha + sum;
    m = mnew;
    #pragma unroll
    for (int r = 0; r < 16; ++r) { o0[r] *= alpha; o1[r] *= alpha; }

    short8 pf[2];
    #pragma unroll
    for (int kk = 0; kk < 2; ++kk) {
      const unsigned A0 = pack2_bf16(s[8 * kk + 0], s[8 * kk + 1]);
      const unsigned B0 = pack2_bf16(s[8 * kk + 2], s[8 * kk + 3]);
      const unsigned C0 = pack2_bf16(s[8 * kk + 4], s[8 * kk + 5]);
      const unsigned D0 = pack2_bf16(s[8 * kk + 6], s[8 * kk + 7]);
      const unsigned sA = (unsigned)__shfl_xor((int)A0, 32);
      const unsigned sB = (unsigned)__shfl_xor((int)B0, 32);
      const unsigned sC = (unsigned)__shfl_xor((int)C0, 32);
      const unsigned sD = (unsigned)__shfl_xor((int)D0, 32);
      Frag fr;
      fr.u[0] = hi ? sC : A0;
      fr.u[1] = hi ? sD : B0;
      fr.u[2] = hi ? C0 : sA;
      fr.u[3] = hi ? D0 : sB;
      pf[kk] = fr.s;
    }

    #pragma unroll
    for (int kk = 0; kk < 2; ++kk) {
      Frag f0, f1;
      #pragma unroll
      for (int j = 0; j < 4; ++j) {
        f0.u[j] = pack2_bf16(vraw[kk * 16 + 2 * j],     vraw[kk * 16 + 2 * j + 1]);
        f1.u[j] = pack2_bf16(vraw[kk * 16 + 8 + 2 * j], vraw[kk * 16 + 8 + 2 * j + 1]);
      }
      o0 = __builtin_amdgcn_mfma_f32_32x32x16_bf16(f0.s, pf[kk], o0, 0, 0, 0);
      o1 = __builtin_amdgcn_mfma_f32_32x32x16_bf16(f1.s, pf[kk], o1, 0, 0, 0);
    }
  }

  if (hi == 0) { mLs[w][l31] = m; lLs[w][l31] = l; }
  #pragma unroll
  for (int r = 0; r < 16; ++r) {
    const int dr = (r & 3) + 8 * (r >> 2) + 4 * hi;
    OLs[w][l31][dr]      = o0[r];
    OLs[w][l31][dr + 32] = o1[r];
  }
  __syncthreads();

  for (int e = tid; e < QB * DHEAD; e += NWF * 64) {
    const int q = e >> 6;
    const int d = e & 63;
    float M = mLs[0][q];
    #pragma unroll
    for (int ww = 1; ww < NWF; ++ww) M = fmaxf(M, mLs[ww][q]);
    float L = 0.f, acc = 0.f;
    #pragma unroll
    for (int ww = 0; ww < NWF; ++ww) {
      const float wgt = exp2f(mLs[ww][q] - M);
      L   += lLs[ww][q] * wgt;
      acc += OLs[ww][q][d] * wgt;
    }
    Og[((size_t)b * Lq + q0 + q) * DHEAD + d] = acc / L;
  }
}

extern "C" void kernel_launch(void* const* d_in, const int* in_sizes, int n_in,
                              void* d_out, int out_size, void* d_ws, size_t ws_size,
                              hipStream_t stream) {
  const float* Q  = (const float*)d_in[0];
  const float* K  = (const float*)d_in[1];
  const float* V  = (const float*)d_in[2];
  const int*   VL = (const int*)d_in[3];
  float* O = (float*)d_out;

  const int B  = in_sizes[3];                  // 8
  const int Lq = in_sizes[0] / (B * DHEAD);    // 2048
  const int Lk = in_sizes[1] / (B * DHEAD);    // 2048
  const int nqt = Lq / QB;                     // 64

  const size_t elemsQ  = (size_t)B * Lq * DHEAD;
  const size_t elemsK  = (size_t)B * Lk * DHEAD;
  const size_t qhBytes = elemsQ * 2;
  const size_t khBytes = elemsK * 2;
  const size_t vtBytes = elemsK * 2;
  const size_t nPart   = (size_t)B * SSEG * nqt;
  const size_t otBytes = nPart * QB * DHEAD * sizeof(float);
  const size_t mlBytes = nPart * QB * sizeof(float) * 2;
  const size_t need    = qhBytes + khBytes + vtBytes + otBytes + mlBytes;

  if (ws_size >= need) {
    unsigned short* Qh = (unsigned short*)d_ws;
    unsigned short* Kh = Qh + elemsQ;
    unsigned short* VT = Kh + elemsK;
    float* OT = (float*)((char*)d_ws + qhBytes + khBytes + vtBytes);
    float* Mp = OT + nPart * QB * DHEAD;
    float* Lp = Mp + nPart * QB;

    const int maxL = (Lq > Lk) ? Lq : Lk;
    dim3 pgrid(maxL / 32, B);
    prep_qkv<<<pgrid, 256, 0, stream>>>(Q, K, V, Qh, Kh, VT, Lq, Lk);
    dim3 g1(nqt, B, SSEG);
    fa_seg<<<g1, NW * 64, 0, stream>>>(Qh, Kh, VT, VL, OT, Mp, Lp, Lq, Lk, nqt);
    dim3 g2(nqt, B);
    fa_combine<<<g2, 256, 0, stream>>>(OT, Mp, Lp, O, Lq, nqt);
  } else {
    dim3 grid(Lq / QB, B);
    fa_fwd<<<grid, NWF * 64, 0, stream>>>(Q, K, V, VL, O, Lq, Lk);
  }
}